// Round 10
// baseline (263.988 us; speedup 1.0000x reference)
//
#include <hip/hip_runtime.h>

#define N_  4096
#define D_  64
#define C_  256

typedef short bf16x8 __attribute__((ext_vector_type(8)));
typedef float f32x4  __attribute__((ext_vector_type(4)));

// Barrier draining only LDS ops (cross-wave P-tile hazard); global register
// prefetches (vf/qf) stay in flight across it.
#define CHEAP_BARRIER() asm volatile("s_waitcnt lgkmcnt(0)\n\ts_barrier" ::: "memory")

__device__ __forceinline__ unsigned short f2bf(float f) {
    union { float f; unsigned int i; } v; v.f = f;
    unsigned int r = v.i + 0x7fffu + ((v.i >> 16) & 1u);
    return (unsigned short)(r >> 16);
}

// ---------- fused prepass (R8/R9, verified twice) ----------
__global__ void prepass_kernel(const float* __restrict__ xq,
                               const float* __restrict__ pg,
                               const float* __restrict__ xv,
                               unsigned short* __restrict__ qbf,
                               unsigned short* __restrict__ pgbf,
                               unsigned short* __restrict__ vt2) {
    const int bid = blockIdx.x;
    const int t   = threadIdx.x;
    if (bid < 512) {
        const float* src = (bid < 256) ? xq : pg;
        unsigned short* dst = (bid < 256) ? qbf : pgbf;
        const int base = (bid & 255) * 1024 + t;
#pragma unroll
        for (int it = 0; it < 4; ++it) {
            const int i = base + it * 256;
            float4 v = ((const float4*)src)[i];
            ushort4 o;
            o.x = f2bf(v.x); o.y = f2bf(v.y); o.z = f2bf(v.z); o.w = f2bf(v.w);
            ((ushort4*)dst)[i] = o;
        }
        return;
    }

    __shared__ unsigned short vs[128 * 66];
    const int vb   = bid - 512;
    const int b    = vb >> 7;
    const int rem  = vb & 127;
    const int jt   = rem >> 2;
    const int cq   = rem & 3;
    const int lane = t & 63;
    const int w    = t >> 6;
    const int l15  = lane & 15;
    const int quad = lane >> 4;

    {
        const int jr = t >> 4;
        const int c0 = (t & 15) * 4;
        const float* src = xv + ((size_t)b * N_ + jt * 128 + jr) * C_ + cq * 64 + c0;
        unsigned short* dst = &vs[jr * 66 + c0];
#pragma unroll
        for (int p = 0; p < 8; ++p) {
            const float4 v4 = *(const float4*)(src + (size_t)p * 16 * C_);
            const unsigned int lo = (unsigned)f2bf(v4.x) | ((unsigned)f2bf(v4.y) << 16);
            const unsigned int hi = (unsigned)f2bf(v4.z) | ((unsigned)f2bf(v4.w) << 16);
            *(unsigned int*)(dst + p * 16 * 66)     = lo;
            *(unsigned int*)(dst + p * 16 * 66 + 2) = hi;
        }
    }
    __syncthreads();

    const int ks = w;
#pragma unroll
    for (int cb = 0; cb < 4; ++cb) {
        const unsigned short* pr = &vs[(ks * 32 + quad * 8) * 66 + cb * 16 + l15];
        const unsigned short e0 = pr[0 * 66], e1 = pr[1 * 66];
        const unsigned short e2 = pr[2 * 66], e3 = pr[3 * 66];
        const unsigned short e4 = pr[4 * 66], e5 = pr[5 * 66];
        const unsigned short e6 = pr[6 * 66], e7 = pr[7 * 66];
        uint4 o;
        o.x = (unsigned)e0 | ((unsigned)e1 << 16);
        o.y = (unsigned)e2 | ((unsigned)e3 << 16);
        o.z = (unsigned)e4 | ((unsigned)e5 << 16);
        o.w = (unsigned)e6 | ((unsigned)e7 << 16);
        const int f = ((b * 32 + jt) * 16 + (cq * 4 + cb)) * 4 + ks;
        *(uint4*)(vt2 + (size_t)f * 512 + lane * 8) = o;
    }
}

// ---------- main: 256 blocks x 1024 thr (16 waves), M=64, j-tile 256 ----------
// R3 per-wave structure (oacc[4][2], vf[4][2], pgf[4][2] -> ~120 VGPR, fits the
// 128 cap) at DOUBLE occupancy: 16 waves/block = 4 waves/SIMD (was 2).
// Wave w = (h=w>>3: j-half of the 256-j tile = own 4 K-slices; oct=w&7: 32-ch
// octant). Each of 16 waves computes S for its own 16-j strip (no S
// duplication); each V frag read exactly once per block; P tile [64][256]
// shorts XOR-swizzled (same bank pattern as R3). One-time 2-way j-half merge
// through the dead P LDS at the end.
__global__ __launch_bounds__(1024, 4) void attn_main(
    const float* __restrict__ g,  const float* __restrict__ x,
    const float* __restrict__ kk, float* __restrict__ out,
    const unsigned short* __restrict__ qbf,
    const unsigned short* __restrict__ pgbf,
    const unsigned short* __restrict__ vt2)
{
    // [0,32768): P buf0; [32768,65536): P buf1 (each 64 x 256 shorts)
    // merge: 8 regions [64][36] f32 (9216 B) = 73728 B, reusing same space
    __shared__ __align__(16) unsigned char smem[73728];
    __shared__ float s_l[64];

    const int t    = threadIdx.x;
    const int lane = t & 63;
    const int w    = t >> 6;            // 0..15
    const int l15  = lane & 15;
    const int quad = lane >> 4;
    const int swz  = (l15 & 7) << 4;
    const int h    = w >> 3;            // j-half 0..1
    const int oct  = w & 7;             // 32-ch octant

    const int bid = blockIdx.x;
    const int b   = bid & 3;
    const int rg  = bid >> 2;
    const size_t rowbase = (size_t)b * N_ + rg * 64;

    if (t < 64) s_l[t] = 0.f;

    // ---- g passthrough: 64 rows x 256 ch over 16 waves ----
#pragma unroll
    for (int it = 0; it < 4; ++it) {
        const int row = it * 16 + w;
        const float4 gv = *(const float4*)(g + (rowbase + row) * C_ + lane * 4);
        *(float4*)(out + (rowbase + row) * (2 * C_) + C_ + lane * 4) = gv;
    }

    // ---- pg B-frags: 4 i-tiles x 2 K-slices, persistent ----
    bf16x8 pgf[4][2];
#pragma unroll
    for (int nt = 0; nt < 4; ++nt)
#pragma unroll
        for (int ks = 0; ks < 2; ++ks)
            pgf[nt][ks] = *(const bf16x8*)(pgbf +
                (rowbase + nt * 16 + l15) * D_ + ks * 32 + quad * 8);

    f32x4 oacc[4][2];                   // 64 rows x wave's 32-ch octant (j-half partial)
#pragma unroll
    for (int mt = 0; mt < 4; ++mt) { oacc[mt][0] = (f32x4){0.f,0.f,0.f,0.f};
                                     oacc[mt][1] = (f32x4){0.f,0.f,0.f,0.f}; }
    float ls[4] = {0.f, 0.f, 0.f, 0.f};

    const unsigned short* qb  = qbf + (size_t)b * N_ * D_;
    const unsigned short* vtb = vt2 + (size_t)b * N_ * C_;
    unsigned short* const pb0 = (unsigned short*)smem;
    unsigned short* const pb1 = (unsigned short*)(smem + 32768);

    // q A-frag: wave's 16-j strip within 256-j tile p
    auto load_q = [&](bf16x8 (&qf)[2], int p) {
        const int pc = (p < 15) ? p : 15;
#pragma unroll
        for (int ks = 0; ks < 2; ++ks)
            qf[ks] = *(const bf16x8*)(qb +
                (size_t)(pc * 256 + w * 16 + l15) * D_ + ks * 32 + quad * 8);
    };
    // V frags: wave's j-half (jt128 = 2p+h), its 32-ch octant, all 4 K-slices
    auto load_v = [&](bf16x8 (&vf)[4][2], int p) {
        const unsigned short* tbase = vtb + (size_t)(2 * p + h) * 32768;
#pragma unroll
        for (int ks = 0; ks < 4; ++ks)
#pragma unroll
            for (int ctl = 0; ctl < 2; ++ctl)
                vf[ks][ctl] = *(const bf16x8*)(tbase +
                    (size_t)(((oct * 2 + ctl) * 4) + ks) * 512 + lane * 8);
    };
    // S for wave's strip: 8 MFMA -> exp -> 4x ds_write_b64 (transposed+swz)
    auto s_step = [&](const bf16x8 (&qf)[2], unsigned short* pbuf) {
        f32x4 sacc[4];
#pragma unroll
        for (int nt = 0; nt < 4; ++nt) sacc[nt] = (f32x4){0.f,0.f,0.f,0.f};
#pragma unroll
        for (int ks = 0; ks < 2; ++ks)
#pragma unroll
            for (int nt = 0; nt < 4; ++nt)
                sacc[nt] = __builtin_amdgcn_mfma_f32_16x16x32_bf16(
                    qf[ks], pgf[nt][ks], sacc[nt], 0, 0, 0);
#pragma unroll
        for (int nt = 0; nt < 4; ++nt) {
            const float p0 = __expf(sacc[nt][0]);
            const float p1 = __expf(sacc[nt][1]);
            const float p2 = __expf(sacc[nt][2]);
            const float p3 = __expf(sacc[nt][3]);
            ls[nt] += (p0 + p1) + (p2 + p3);
            ushort4 pk;
            pk.x = f2bf(p0); pk.y = f2bf(p1); pk.z = f2bf(p2); pk.w = f2bf(p3);
            const int wb = ((nt * 16 + l15) * 512 + (w * 16 + quad * 4) * 2) ^ swz;
            *(ushort4*)((char*)pbuf + wb) = pk;
        }
    };
    // PV: wave's j-half (4 K-slices) x 4 mt x 2 ctl = 16 ds_read_b128 + 32 MFMA
    auto pv_step = [&](const bf16x8 (&vf)[4][2], const unsigned short* pbuf) {
#pragma unroll
        for (int ks = 0; ks < 4; ++ks) {
            bf16x8 pa[4];
#pragma unroll
            for (int mt = 0; mt < 4; ++mt) {
                const int rb = ((mt * 16 + l15) * 512 + h * 256 + ks * 64 + quad * 16) ^ swz;
                pa[mt] = *(const bf16x8*)((const char*)pbuf + rb);
            }
#pragma unroll
            for (int mt = 0; mt < 4; ++mt) {
                oacc[mt][0] = __builtin_amdgcn_mfma_f32_16x16x32_bf16(pa[mt], vf[ks][0], oacc[mt][0], 0, 0, 0);
                oacc[mt][1] = __builtin_amdgcn_mfma_f32_16x16x32_bf16(pa[mt], vf[ks][1], oacc[mt][1], 0, 0, 0);
            }
        }
    };

    bf16x8 qfA[2], qfB[2], vfA[4][2], vfB[4][2];

    // ---- prologue: S(0) -> buf0 ----
    load_q(qfA, 0);
    load_v(vfA, 0);
    s_step(qfA, pb0);
    load_q(qfB, 1);
    CHEAP_BARRIER();

    // ---- pipelined main loop: 2 tiles per iteration (16 tiles of 256 j) ----
#pragma unroll 1
    for (int pp = 0; pp < 7; ++pp) {
        const int p = 2 * pp;
        // even: PV(p) + S(p+1)
        load_v(vfB, p + 1);
        load_q(qfA, p + 2);
        s_step(qfB, pb1);
        pv_step(vfA, pb0);
        CHEAP_BARRIER();
        // odd: PV(p+1) + S(p+2)
        load_v(vfA, p + 2);
        load_q(qfB, p + 3);
        s_step(qfA, pb0);
        pv_step(vfB, pb1);
        CHEAP_BARRIER();
    }
    // tail: tile 14 then 15
    load_v(vfB, 15);
    s_step(qfB, pb1);
    pv_step(vfA, pb0);
    CHEAP_BARRIER();
    pv_step(vfB, pb1);

    // ---- l reduction: strips partition j; sum quads then 16 waves ----
#pragma unroll
    for (int nt = 0; nt < 4; ++nt) {
        float s = ls[nt];
        s += __shfl_xor(s, 16);
        s += __shfl_xor(s, 32);
        if (lane < 16) atomicAdd(&s_l[nt * 16 + lane], s);
    }
    __syncthreads();   // s_l final; P buffers dead -> reuse for merge

    // ---- j-half merge + epilogue ----
    float* Rg = (float*)(smem + (size_t)oct * 9216);   // [64][36] f32 per octant
    if (h == 1) {
#pragma unroll
        for (int mt = 0; mt < 4; ++mt)
#pragma unroll
            for (int ctl = 0; ctl < 2; ++ctl)
#pragma unroll
                for (int r = 0; r < 4; ++r)
                    Rg[(mt * 16 + quad * 4 + r) * 36 + ctl * 16 + l15] = oacc[mt][ctl][r];
    }
    __syncthreads();
    if (h == 0) {
        const float kval = kk[0];
#pragma unroll
        for (int mt = 0; mt < 4; ++mt)
#pragma unroll
            for (int r = 0; r < 4; ++r) {
                const int m = mt * 16 + quad * 4 + r;
                const float linv = 1.f / s_l[m];
                const size_t row = rowbase + m;
#pragma unroll
                for (int ctl = 0; ctl < 2; ++ctl) {
                    const int c = oct * 32 + ctl * 16 + l15;
                    const float sum = oacc[mt][ctl][r] + Rg[m * 36 + ctl * 16 + l15];
                    out[row * (2 * C_) + c] = kval * (sum * linv) + x[row * C_ + c];
                }
            }
    }
}

// ---------- fallback (round-2 vector kernel) if workspace too small ----------
#define ROWS 4
#define FNT  256
__global__ __launch_bounds__(FNT, 2) void attn_fallback(
    const float* __restrict__ g, const float* __restrict__ x,
    const float* __restrict__ xq, const float* __restrict__ pg,
    const float* __restrict__ xv, const float* __restrict__ kk,
    float* __restrict__ out)
{
    __shared__ __align__(16) float s_pg[ROWS][D_];
    __shared__ __align__(16) float s_sc[N_ * ROWS];
    __shared__ float s_rmax[4][ROWS];
    __shared__ float s_rsum[4][ROWS];

    const int t = threadIdx.x, lane = t & 63, w = t >> 6, blk = blockIdx.x;
    const int b = blk >> 10, i0 = (blk & 1023) * ROWS;
    const size_t rowbase = (size_t)b * N_ + i0;
    {
        const int r = t >> 6, cc = (t & 63) * 4;
        const float4 gv = *(const float4*)(g + (rowbase + r) * C_ + cc);
        *(float4*)(out + (rowbase + r) * (2 * C_) + C_ + cc) = gv;
    }
    { const int r = t >> 6, d = t & 63; s_pg[r][d] = pg[(rowbase + r) * D_ + d]; }
    __syncthreads();
    const float* qb = xq + (size_t)b * N_ * D_;
    float lmax[ROWS];
#pragma unroll
    for (int r = 0; r < ROWS; ++r) lmax[r] = -1e30f;
    for (int jj = 0; jj < N_ / FNT; ++jj) {
        const int j = t + jj * FNT;
        const float4* q4p = (const float4*)(qb + (size_t)j * D_);
        float s[ROWS] = {0.f, 0.f, 0.f, 0.f};
#pragma unroll
        for (int u = 0; u < D_ / 8; ++u) {
            const float4 qa = q4p[u * 2], qc = q4p[u * 2 + 1];
#pragma unroll
            for (int r = 0; r < ROWS; ++r) {
                const float4 pa = *(const float4*)&s_pg[r][u * 8];
                const float4 pb = *(const float4*)&s_pg[r][u * 8 + 4];
                s[r] += qa.x * pa.x + qa.y * pa.y + qa.z * pa.z + qa.w * pa.w
                      + qc.x * pb.x + qc.y * pb.y + qc.z * pb.z + qc.w * pb.w;
            }
        }
        *(float4*)&s_sc[j * ROWS] = make_float4(s[0], s[1], s[2], s[3]);
#pragma unroll
        for (int r = 0; r < ROWS; ++r) lmax[r] = fmaxf(lmax[r], s[r]);
    }
#pragma unroll
    for (int r = 0; r < ROWS; ++r) {
        float m = lmax[r];
        for (int o = 32; o > 0; o >>= 1) m = fmaxf(m, __shfl_down(m, o));
        if (lane == 0) s_rmax[w][r] = m;
    }
    __syncthreads();
    float bmax[ROWS];
#pragma unroll
    for (int r = 0; r < ROWS; ++r)
        bmax[r] = fmaxf(fmaxf(s_rmax[0][r], s_rmax[1][r]), fmaxf(s_rmax[2][r], s_rmax[3][r]));
    float lsum[ROWS] = {0.f, 0.f, 0.f, 0.f};
    for (int jj = 0; jj < N_ / FNT; ++jj) {
        const int j = t + jj * FNT;
        float4 s4 = *(const float4*)&s_sc[j * ROWS];
        s4.x = __expf(s4.x - bmax[0]); s4.y = __expf(s4.y - bmax[1]);
        s4.z = __expf(s4.z - bmax[2]); s4.w = __expf(s4.w - bmax[3]);
        *(float4*)&s_sc[j * ROWS] = s4;
        lsum[0] += s4.x; lsum[1] += s4.y; lsum[2] += s4.z; lsum[3] += s4.w;
    }
#pragma unroll
    for (int r = 0; r < ROWS; ++r) {
        float sm = lsum[r];
        for (int o = 32; o > 0; o >>= 1) sm += __shfl_down(sm, o);
        if (lane == 0) s_rsum[w][r] = sm;
    }
    __syncthreads();
    float rinv[ROWS];
#pragma unroll
    for (int r = 0; r < ROWS; ++r)
        rinv[r] = 1.f / (s_rsum[0][r] + s_rsum[1][r] + s_rsum[2][r] + s_rsum[3][r]);
    const int jg = lane >> 4;
    const int c0 = (w * 16 + (lane & 15)) * 4;
    const float* vb = xv + (size_t)b * N_ * C_;
    float acc[ROWS][4];
#pragma unroll
    for (int r = 0; r < ROWS; ++r)
#pragma unroll
        for (int q = 0; q < 4; ++q) acc[r][q] = 0.f;
#pragma unroll 4
    for (int jj = 0; jj < N_ / 4; ++jj) {
        const int j = jj * 4 + jg;
        const float4 p4 = *(const float4*)&s_sc[j * ROWS];
        const float4 v4 = *(const float4*)(vb + (size_t)j * C_ + c0);
        acc[0][0] += p4.x * v4.x; acc[0][1] += p4.x * v4.y; acc[0][2] += p4.x * v4.z; acc[0][3] += p4.x * v4.w;
        acc[1][0] += p4.y * v4.x; acc[1][1] += p4.y * v4.y; acc[1][2] += p4.y * v4.z; acc[1][3] += p4.y * v4.w;
        acc[2][0] += p4.z * v4.x; acc[2][1] += p4.z * v4.y; acc[2][2] += p4.z * v4.z; acc[2][3] += p4.z * v4.w;
        acc[3][0] += p4.w * v4.x; acc[3][1] += p4.w * v4.y; acc[3][2] += p4.w * v4.z; acc[3][3] += p4.w * v4.w;
    }
#pragma unroll
    for (int r = 0; r < ROWS; ++r)
#pragma unroll
        for (int q = 0; q < 4; ++q) {
            acc[r][q] += __shfl_xor(acc[r][q], 16);
            acc[r][q] += __shfl_xor(acc[r][q], 32);
        }
    const float kval = kk[0];
    if (lane < 16) {
        const int c = (w * 16 + lane) * 4;
#pragma unroll
        for (int r = 0; r < ROWS; ++r) {
            const float4 xv4 = *(const float4*)(x + (rowbase + r) * C_ + c);
            float4 ov;
            ov.x = kval * (acc[r][0] * rinv[r]) + xv4.x;
            ov.y = kval * (acc[r][1] * rinv[r]) + xv4.y;
            ov.z = kval * (acc[r][2] * rinv[r]) + xv4.z;
            ov.w = kval * (acc[r][3] * rinv[r]) + xv4.w;
            *(float4*)(out + (rowbase + r) * (2 * C_) + c) = ov;
        }
    }
}

extern "C" void kernel_launch(void* const* d_in, const int* in_sizes, int n_in,
                              void* d_out, int out_size, void* d_ws, size_t ws_size,
                              hipStream_t stream) {
    const float* g  = (const float*)d_in[0];
    const float* x  = (const float*)d_in[1];
    const float* xq = (const float*)d_in[2];
    const float* pg = (const float*)d_in[3];
    const float* xv = (const float*)d_in[4];
    const float* kk = (const float*)d_in[5];
    float* out = (float*)d_out;

    const int B = in_sizes[0] / (N_ * C_);   // 4
    const size_t qn = (size_t)B * N_ * D_;
    const size_t vn = (size_t)B * N_ * C_;
    const size_t need = (2 * qn + vn) * sizeof(unsigned short);

    if (B != 4 || ws_size < need) {
        attn_fallback<<<dim3(B * (N_ / ROWS)), FNT, 0, stream>>>(g, x, xq, pg, xv, kk, out);
        return;
    }

    unsigned short* qbf  = (unsigned short*)d_ws;
    unsigned short* pgbf = qbf + qn;
    unsigned short* vt2  = pgbf + qn;

    prepass_kernel<<<dim3(512 + B * 128), 256, 0, stream>>>(xq, pg, xv, qbf, pgbf, vt2);
    attn_main<<<dim3(B * (N_ / 64)), 1024, 0, stream>>>(g, x, kk, out, qbf, pgbf, vt2);
}

// Round 11
// 263.042 us; speedup vs baseline: 1.0036x; 1.0036x over previous
//
#include <hip/hip_runtime.h>

#define N_  4096
#define D_  64
#define C_  256

typedef short bf16x8 __attribute__((ext_vector_type(8)));
typedef float f32x4  __attribute__((ext_vector_type(4)));

// Barrier draining only LDS ops (cross-wave P-tile hazard); global register
// prefetches (vf/qf) stay in flight across it.
#define CHEAP_BARRIER() asm volatile("s_waitcnt lgkmcnt(0)\n\ts_barrier" ::: "memory")

__device__ __forceinline__ unsigned short f2bf(float f) {
    union { float f; unsigned int i; } v; v.f = f;
    unsigned int r = v.i + 0x7fffu + ((v.i >> 16) & 1u);
    return (unsigned short)(r >> 16);
}

// ---------- fused prepass (R8/R9, verified) ----------
__global__ void prepass_kernel(const float* __restrict__ xq,
                               const float* __restrict__ pg,
                               const float* __restrict__ xv,
                               unsigned short* __restrict__ qbf,
                               unsigned short* __restrict__ pgbf,
                               unsigned short* __restrict__ vt2) {
    const int bid = blockIdx.x;
    const int t   = threadIdx.x;
    if (bid < 512) {
        const float* src = (bid < 256) ? xq : pg;
        unsigned short* dst = (bid < 256) ? qbf : pgbf;
        const int base = (bid & 255) * 1024 + t;
#pragma unroll
        for (int it = 0; it < 4; ++it) {
            const int i = base + it * 256;
            float4 v = ((const float4*)src)[i];
            ushort4 o;
            o.x = f2bf(v.x); o.y = f2bf(v.y); o.z = f2bf(v.z); o.w = f2bf(v.w);
            ((ushort4*)dst)[i] = o;
        }
        return;
    }

    __shared__ unsigned short vs[128 * 66];
    const int vb   = bid - 512;
    const int b    = vb >> 7;
    const int rem  = vb & 127;
    const int jt   = rem >> 2;
    const int cq   = rem & 3;
    const int lane = t & 63;
    const int w    = t >> 6;
    const int l15  = lane & 15;
    const int quad = lane >> 4;

    {
        const int jr = t >> 4;
        const int c0 = (t & 15) * 4;
        const float* src = xv + ((size_t)b * N_ + jt * 128 + jr) * C_ + cq * 64 + c0;
        unsigned short* dst = &vs[jr * 66 + c0];
#pragma unroll
        for (int p = 0; p < 8; ++p) {
            const float4 v4 = *(const float4*)(src + (size_t)p * 16 * C_);
            const unsigned int lo = (unsigned)f2bf(v4.x) | ((unsigned)f2bf(v4.y) << 16);
            const unsigned int hi = (unsigned)f2bf(v4.z) | ((unsigned)f2bf(v4.w) << 16);
            *(unsigned int*)(dst + p * 16 * 66)     = lo;
            *(unsigned int*)(dst + p * 16 * 66 + 2) = hi;
        }
    }
    __syncthreads();

    const int ks = w;
#pragma unroll
    for (int cb = 0; cb < 4; ++cb) {
        const unsigned short* pr = &vs[(ks * 32 + quad * 8) * 66 + cb * 16 + l15];
        const unsigned short e0 = pr[0 * 66], e1 = pr[1 * 66];
        const unsigned short e2 = pr[2 * 66], e3 = pr[3 * 66];
        const unsigned short e4 = pr[4 * 66], e5 = pr[5 * 66];
        const unsigned short e6 = pr[6 * 66], e7 = pr[7 * 66];
        uint4 o;
        o.x = (unsigned)e0 | ((unsigned)e1 << 16);
        o.y = (unsigned)e2 | ((unsigned)e3 << 16);
        o.z = (unsigned)e4 | ((unsigned)e5 << 16);
        o.w = (unsigned)e6 | ((unsigned)e7 << 16);
        const int f = ((b * 32 + jt) * 16 + (cq * 4 + cb)) * 4 + ks;
        *(uint4*)(vt2 + (size_t)f * 512 + lane * 8) = o;
    }
}

// ---------- main: 256 blocks x 1024 thr (16 waves), M=64, j-tile 256 ----------
// R10's design (functionally verified: passed) with the launch-bounds bug
// fixed: __launch_bounds__(1024, 1). R10's (1024,4) was interpreted as min
// 4 BLOCKS/CU -> 8 waves/SIMD -> 64-VGPR cap -> catastrophic spill (FETCH
// 344 GB). With min 1 block: 4 waves/SIMD co-resident -> hard cap 128; the
// per-wave footprint (~120, same as R3's 116) fits with NO spill.
// Wave w = (h=w>>3: j-half of the 256-j tile = own 4 K-slices; oct=w&7: 32-ch
// octant). Each of 16 waves computes S for its own 16-j strip (no S
// duplication); each V frag read exactly once per block; P tile [64][256]
// shorts XOR-swizzled. One-time 2-way j-half merge through dead P LDS.
__global__ __launch_bounds__(1024, 1) void attn_main(
    const float* __restrict__ g,  const float* __restrict__ x,
    const float* __restrict__ kk, float* __restrict__ out,
    const unsigned short* __restrict__ qbf,
    const unsigned short* __restrict__ pgbf,
    const unsigned short* __restrict__ vt2)
{
    // [0,32768): P buf0; [32768,65536): P buf1 (each 64 x 256 shorts)
    // merge: 8 regions [64][36] f32 (9216 B) = 73728 B, reusing same space
    __shared__ __align__(16) unsigned char smem[73728];
    __shared__ float s_l[64];

    const int t    = threadIdx.x;
    const int lane = t & 63;
    const int w    = t >> 6;            // 0..15
    const int l15  = lane & 15;
    const int quad = lane >> 4;
    const int swz  = (l15 & 7) << 4;
    const int h    = w >> 3;            // j-half 0..1
    const int oct  = w & 7;             // 32-ch octant

    const int bid = blockIdx.x;
    const int b   = bid & 3;
    const int rg  = bid >> 2;
    const size_t rowbase = (size_t)b * N_ + rg * 64;

    if (t < 64) s_l[t] = 0.f;

    // ---- g passthrough: 64 rows x 256 ch over 16 waves ----
#pragma unroll
    for (int it = 0; it < 4; ++it) {
        const int row = it * 16 + w;
        const float4 gv = *(const float4*)(g + (rowbase + row) * C_ + lane * 4);
        *(float4*)(out + (rowbase + row) * (2 * C_) + C_ + lane * 4) = gv;
    }

    // ---- pg B-frags: 4 i-tiles x 2 K-slices, persistent ----
    bf16x8 pgf[4][2];
#pragma unroll
    for (int nt = 0; nt < 4; ++nt)
#pragma unroll
        for (int ks = 0; ks < 2; ++ks)
            pgf[nt][ks] = *(const bf16x8*)(pgbf +
                (rowbase + nt * 16 + l15) * D_ + ks * 32 + quad * 8);

    f32x4 oacc[4][2];                   // 64 rows x wave's 32-ch octant (j-half partial)
#pragma unroll
    for (int mt = 0; mt < 4; ++mt) { oacc[mt][0] = (f32x4){0.f,0.f,0.f,0.f};
                                     oacc[mt][1] = (f32x4){0.f,0.f,0.f,0.f}; }
    float ls[4] = {0.f, 0.f, 0.f, 0.f};

    const unsigned short* qb  = qbf + (size_t)b * N_ * D_;
    const unsigned short* vtb = vt2 + (size_t)b * N_ * C_;
    unsigned short* const pb0 = (unsigned short*)smem;
    unsigned short* const pb1 = (unsigned short*)(smem + 32768);

    // q A-frag: wave's 16-j strip within 256-j tile p
    auto load_q = [&](bf16x8 (&qf)[2], int p) {
        const int pc = (p < 15) ? p : 15;
#pragma unroll
        for (int ks = 0; ks < 2; ++ks)
            qf[ks] = *(const bf16x8*)(qb +
                (size_t)(pc * 256 + w * 16 + l15) * D_ + ks * 32 + quad * 8);
    };
    // V frags: wave's j-half (jt128 = 2p+h), its 32-ch octant, all 4 K-slices
    auto load_v = [&](bf16x8 (&vf)[4][2], int p) {
        const unsigned short* tbase = vtb + (size_t)(2 * p + h) * 32768;
#pragma unroll
        for (int ks = 0; ks < 4; ++ks)
#pragma unroll
            for (int ctl = 0; ctl < 2; ++ctl)
                vf[ks][ctl] = *(const bf16x8*)(tbase +
                    (size_t)(((oct * 2 + ctl) * 4) + ks) * 512 + lane * 8);
    };
    // S for wave's strip: 8 MFMA -> exp -> 4x ds_write_b64 (transposed+swz)
    auto s_step = [&](const bf16x8 (&qf)[2], unsigned short* pbuf) {
        f32x4 sacc[4];
#pragma unroll
        for (int nt = 0; nt < 4; ++nt) sacc[nt] = (f32x4){0.f,0.f,0.f,0.f};
#pragma unroll
        for (int ks = 0; ks < 2; ++ks)
#pragma unroll
            for (int nt = 0; nt < 4; ++nt)
                sacc[nt] = __builtin_amdgcn_mfma_f32_16x16x32_bf16(
                    qf[ks], pgf[nt][ks], sacc[nt], 0, 0, 0);
#pragma unroll
        for (int nt = 0; nt < 4; ++nt) {
            const float p0 = __expf(sacc[nt][0]);
            const float p1 = __expf(sacc[nt][1]);
            const float p2 = __expf(sacc[nt][2]);
            const float p3 = __expf(sacc[nt][3]);
            ls[nt] += (p0 + p1) + (p2 + p3);
            ushort4 pk;
            pk.x = f2bf(p0); pk.y = f2bf(p1); pk.z = f2bf(p2); pk.w = f2bf(p3);
            const int wb = ((nt * 16 + l15) * 512 + (w * 16 + quad * 4) * 2) ^ swz;
            *(ushort4*)((char*)pbuf + wb) = pk;
        }
    };
    // PV: wave's j-half (4 K-slices) x 4 mt x 2 ctl = 16 ds_read_b128 + 32 MFMA
    auto pv_step = [&](const bf16x8 (&vf)[4][2], const unsigned short* pbuf) {
#pragma unroll
        for (int ks = 0; ks < 4; ++ks) {
            bf16x8 pa[4];
#pragma unroll
            for (int mt = 0; mt < 4; ++mt) {
                const int rb = ((mt * 16 + l15) * 512 + h * 256 + ks * 64 + quad * 16) ^ swz;
                pa[mt] = *(const bf16x8*)((const char*)pbuf + rb);
            }
#pragma unroll
            for (int mt = 0; mt < 4; ++mt) {
                oacc[mt][0] = __builtin_amdgcn_mfma_f32_16x16x32_bf16(pa[mt], vf[ks][0], oacc[mt][0], 0, 0, 0);
                oacc[mt][1] = __builtin_amdgcn_mfma_f32_16x16x32_bf16(pa[mt], vf[ks][1], oacc[mt][1], 0, 0, 0);
            }
        }
    };

    bf16x8 qfA[2], qfB[2], vfA[4][2], vfB[4][2];

    // ---- prologue: S(0) -> buf0 ----
    load_q(qfA, 0);
    load_v(vfA, 0);
    s_step(qfA, pb0);
    load_q(qfB, 1);
    CHEAP_BARRIER();

    // ---- pipelined main loop: 2 tiles per iteration (16 tiles of 256 j) ----
#pragma unroll 1
    for (int pp = 0; pp < 7; ++pp) {
        const int p = 2 * pp;
        // even: PV(p) + S(p+1)
        load_v(vfB, p + 1);
        load_q(qfA, p + 2);
        s_step(qfB, pb1);
        pv_step(vfA, pb0);
        CHEAP_BARRIER();
        // odd: PV(p+1) + S(p+2)
        load_v(vfA, p + 2);
        load_q(qfB, p + 3);
        s_step(qfA, pb0);
        pv_step(vfB, pb1);
        CHEAP_BARRIER();
    }
    // tail: tile 14 then 15
    load_v(vfB, 15);
    s_step(qfB, pb1);
    pv_step(vfA, pb0);
    CHEAP_BARRIER();
    pv_step(vfB, pb1);

    // ---- l reduction: strips partition j; sum quads then 16 waves ----
#pragma unroll
    for (int nt = 0; nt < 4; ++nt) {
        float s = ls[nt];
        s += __shfl_xor(s, 16);
        s += __shfl_xor(s, 32);
        if (lane < 16) atomicAdd(&s_l[nt * 16 + lane], s);
    }
    __syncthreads();   // s_l final; P buffers dead -> reuse for merge

    // ---- j-half merge + epilogue ----
    float* Rg = (float*)(smem + (size_t)oct * 9216);   // [64][36] f32 per octant
    if (h == 1) {
#pragma unroll
        for (int mt = 0; mt < 4; ++mt)
#pragma unroll
            for (int ctl = 0; ctl < 2; ++ctl)
#pragma unroll
                for (int r = 0; r < 4; ++r)
                    Rg[(mt * 16 + quad * 4 + r) * 36 + ctl * 16 + l15] = oacc[mt][ctl][r];
    }
    __syncthreads();
    if (h == 0) {
        const float kval = kk[0];
#pragma unroll
        for (int mt = 0; mt < 4; ++mt)
#pragma unroll
            for (int r = 0; r < 4; ++r) {
                const int m = mt * 16 + quad * 4 + r;
                const float linv = 1.f / s_l[m];
                const size_t row = rowbase + m;
#pragma unroll
                for (int ctl = 0; ctl < 2; ++ctl) {
                    const int c = oct * 32 + ctl * 16 + l15;
                    const float sum = oacc[mt][ctl][r] + Rg[m * 36 + ctl * 16 + l15];
                    out[row * (2 * C_) + c] = kval * (sum * linv) + x[row * C_ + c];
                }
            }
    }
}

// ---------- fallback (round-2 vector kernel) if workspace too small ----------
#define ROWS 4
#define FNT  256
__global__ __launch_bounds__(FNT, 2) void attn_fallback(
    const float* __restrict__ g, const float* __restrict__ x,
    const float* __restrict__ xq, const float* __restrict__ pg,
    const float* __restrict__ xv, const float* __restrict__ kk,
    float* __restrict__ out)
{
    __shared__ __align__(16) float s_pg[ROWS][D_];
    __shared__ __align__(16) float s_sc[N_ * ROWS];
    __shared__ float s_rmax[4][ROWS];
    __shared__ float s_rsum[4][ROWS];

    const int t = threadIdx.x, lane = t & 63, w = t >> 6, blk = blockIdx.x;
    const int b = blk >> 10, i0 = (blk & 1023) * ROWS;
    const size_t rowbase = (size_t)b * N_ + i0;
    {
        const int r = t >> 6, cc = (t & 63) * 4;
        const float4 gv = *(const float4*)(g + (rowbase + r) * C_ + cc);
        *(float4*)(out + (rowbase + r) * (2 * C_) + C_ + cc) = gv;
    }
    { const int r = t >> 6, d = t & 63; s_pg[r][d] = pg[(rowbase + r) * D_ + d]; }
    __syncthreads();
    const float* qb = xq + (size_t)b * N_ * D_;
    float lmax[ROWS];
#pragma unroll
    for (int r = 0; r < ROWS; ++r) lmax[r] = -1e30f;
    for (int jj = 0; jj < N_ / FNT; ++jj) {
        const int j = t + jj * FNT;
        const float4* q4p = (const float4*)(qb + (size_t)j * D_);
        float s[ROWS] = {0.f, 0.f, 0.f, 0.f};
#pragma unroll
        for (int u = 0; u < D_ / 8; ++u) {
            const float4 qa = q4p[u * 2], qc = q4p[u * 2 + 1];
#pragma unroll
            for (int r = 0; r < ROWS; ++r) {
                const float4 pa = *(const float4*)&s_pg[r][u * 8];
                const float4 pb = *(const float4*)&s_pg[r][u * 8 + 4];
                s[r] += qa.x * pa.x + qa.y * pa.y + qa.z * pa.z + qa.w * pa.w
                      + qc.x * pb.x + qc.y * pb.y + qc.z * pb.z + qc.w * pb.w;
            }
        }
        *(float4*)&s_sc[j * ROWS] = make_float4(s[0], s[1], s[2], s[3]);
#pragma unroll
        for (int r = 0; r < ROWS; ++r) lmax[r] = fmaxf(lmax[r], s[r]);
    }
#pragma unroll
    for (int r = 0; r < ROWS; ++r) {
        float m = lmax[r];
        for (int o = 32; o > 0; o >>= 1) m = fmaxf(m, __shfl_down(m, o));
        if (lane == 0) s_rmax[w][r] = m;
    }
    __syncthreads();
    float bmax[ROWS];
#pragma unroll
    for (int r = 0; r < ROWS; ++r)
        bmax[r] = fmaxf(fmaxf(s_rmax[0][r], s_rmax[1][r]), fmaxf(s_rmax[2][r], s_rmax[3][r]));
    float lsum[ROWS] = {0.f, 0.f, 0.f, 0.f};
    for (int jj = 0; jj < N_ / FNT; ++jj) {
        const int j = t + jj * FNT;
        float4 s4 = *(const float4*)&s_sc[j * ROWS];
        s4.x = __expf(s4.x - bmax[0]); s4.y = __expf(s4.y - bmax[1]);
        s4.z = __expf(s4.z - bmax[2]); s4.w = __expf(s4.w - bmax[3]);
        *(float4*)&s_sc[j * ROWS] = s4;
        lsum[0] += s4.x; lsum[1] += s4.y; lsum[2] += s4.z; lsum[3] += s4.w;
    }
#pragma unroll
    for (int r = 0; r < ROWS; ++r) {
        float sm = lsum[r];
        for (int o = 32; o > 0; o >>= 1) sm += __shfl_down(sm, o);
        if (lane == 0) s_rsum[w][r] = sm;
    }
    __syncthreads();
    float rinv[ROWS];
#pragma unroll
    for (int r = 0; r < ROWS; ++r)
        rinv[r] = 1.f / (s_rsum[0][r] + s_rsum[1][r] + s_rsum[2][r] + s_rsum[3][r]);
    const int jg = lane >> 4;
    const int c0 = (w * 16 + (lane & 15)) * 4;
    const float* vb = xv + (size_t)b * N_ * C_;
    float acc[ROWS][4];
#pragma unroll
    for (int r = 0; r < ROWS; ++r)
#pragma unroll
        for (int q = 0; q < 4; ++q) acc[r][q] = 0.f;
#pragma unroll 4
    for (int jj = 0; jj < N_ / 4; ++jj) {
        const int j = jj * 4 + jg;
        const float4 p4 = *(const float4*)&s_sc[j * ROWS];
        const float4 v4 = *(const float4*)(vb + (size_t)j * C_ + c0);
        acc[0][0] += p4.x * v4.x; acc[0][1] += p4.x * v4.y; acc[0][2] += p4.x * v4.z; acc[0][3] += p4.x * v4.w;
        acc[1][0] += p4.y * v4.x; acc[1][1] += p4.y * v4.y; acc[1][2] += p4.y * v4.z; acc[1][3] += p4.y * v4.w;
        acc[2][0] += p4.z * v4.x; acc[2][1] += p4.z * v4.y; acc[2][2] += p4.z * v4.z; acc[2][3] += p4.z * v4.w;
        acc[3][0] += p4.w * v4.x; acc[3][1] += p4.w * v4.y; acc[3][2] += p4.w * v4.z; acc[3][3] += p4.w * v4.w;
    }
#pragma unroll
    for (int r = 0; r < ROWS; ++r)
#pragma unroll
        for (int q = 0; q < 4; ++q) {
            acc[r][q] += __shfl_xor(acc[r][q], 16);
            acc[r][q] += __shfl_xor(acc[r][q], 32);
        }
    const float kval = kk[0];
    if (lane < 16) {
        const int c = (w * 16 + lane) * 4;
#pragma unroll
        for (int r = 0; r < ROWS; ++r) {
            const float4 xv4 = *(const float4*)(x + (rowbase + r) * C_ + c);
            float4 ov;
            ov.x = kval * (acc[r][0] * rinv[r]) + xv4.x;
            ov.y = kval * (acc[r][1] * rinv[r]) + xv4.y;
            ov.z = kval * (acc[r][2] * rinv[r]) + xv4.z;
            ov.w = kval * (acc[r][3] * rinv[r]) + xv4.w;
            *(float4*)(out + (rowbase + r) * (2 * C_) + c) = ov;
        }
    }
}

extern "C" void kernel_launch(void* const* d_in, const int* in_sizes, int n_in,
                              void* d_out, int out_size, void* d_ws, size_t ws_size,
                              hipStream_t stream) {
    const float* g  = (const float*)d_in[0];
    const float* x  = (const float*)d_in[1];
    const float* xq = (const float*)d_in[2];
    const float* pg = (const float*)d_in[3];
    const float* xv = (const float*)d_in[4];
    const float* kk = (const float*)d_in[5];
    float* out = (float*)d_out;

    const int B = in_sizes[0] / (N_ * C_);   // 4
    const size_t qn = (size_t)B * N_ * D_;
    const size_t vn = (size_t)B * N_ * C_;
    const size_t need = (2 * qn + vn) * sizeof(unsigned short);

    if (B != 4 || ws_size < need) {
        attn_fallback<<<dim3(B * (N_ / ROWS)), FNT, 0, stream>>>(g, x, xq, pg, xv, kk, out);
        return;
    }

    unsigned short* qbf  = (unsigned short*)d_ws;
    unsigned short* pgbf = qbf + qn;
    unsigned short* vt2  = pgbf + qn;

    prepass_kernel<<<dim3(512 + B * 128), 256, 0, stream>>>(xq, pg, xv, qbf, pgbf, vt2);
    attn_main<<<dim3(B * (N_ / 64)), 1024, 0, stream>>>(g, x, kk, out, qbf, pgbf, vt2);
}